// Round 3
// baseline (525.222 us; speedup 1.0000x reference)
//
#include <hip/hip_runtime.h>

#define N_EDGES 1000000
#define HID 128
#define ME 64          // edges per block

typedef unsigned short ushort;
typedef unsigned int uint;
typedef __attribute__((ext_vector_type(8))) short short8;
typedef __attribute__((ext_vector_type(4))) float f32x4;

__device__ __forceinline__ float blo(uint u) { return __builtin_bit_cast(float, u << 16); }
__device__ __forceinline__ float bhi(uint u) { return __builtin_bit_cast(float, u & 0xffff0000u); }
__device__ __forceinline__ ushort f2bfbits(float f) {
  uint u = __builtin_bit_cast(uint, f);
  return (ushort)((u + 0x7fffu + ((u >> 16) & 1u)) >> 16);  // RNE
}
__device__ __forceinline__ uint cvtpk(float a, float b) {
  uint r;
  asm("v_cvt_pk_bf16_f32 %0, %1, %2" : "=v"(r) : "v"(a), "v"(b));
  return r;  // lo = bf16(a), hi = bf16(b)
}
// XOR-swizzled element index into a [64][128] ushort LDS tile.
// Row stride 256B is bank-degenerate; XOR of elem bits 3..5 with (r&7)
// spreads 8 consecutive rows across all 32 banks. Bijective for any
// aligned group of <=8 elems that doesn't cross an 8-elem boundary.
__device__ __forceinline__ int sidx(int r, int c) {
  return r * 128 + (c ^ ((r & 7) << 3));
}

// Pack W (row-major [K][128] f32) into B-fragment order for mfma_f32_16x16x32_bf16.
// W1p kb 0..15: k = kb*32 + (lane>>4)*8 + j (zs,zd,prod,absdiff).
// W1p kb 16..17 (tail chunk, 64 cols): c = (kb-16)*32+(lane>>4)*8+j;
//   c==0 -> k512 (dist); c in [2,34) -> k 511+c (lr_emb); else zero row.
__global__ void prep_kernel(const float* __restrict__ W1, const float* __restrict__ W2,
                            ushort* __restrict__ W1p, ushort* __restrict__ W2p) {
  const int t = blockIdx.x * blockDim.x + threadIdx.x;
  const int n1 = 18 * 8 * 64 * 8;
  if (t < n1) {
    const int j = t & 7, lane = (t >> 3) & 63, nt = (t >> 9) & 7, kb = t >> 12;
    const int col = nt * 16 + (lane & 15);
    float val = 0.f;
    if (kb < 16) {
      const int k = kb * 32 + (lane >> 4) * 8 + j;
      val = W1[k * HID + col];
    } else {
      const int c = (kb - 16) * 32 + (lane >> 4) * 8 + j;
      const int k = (c == 0) ? 512 : ((c >= 2 && c < 34) ? (511 + c) : -1);
      if (k >= 0) val = W1[k * HID + col];
    }
    W1p[t] = f2bfbits(val);
  } else {
    const int t2 = t - n1;
    if (t2 < 4 * 8 * 64 * 8) {
      const int j = t2 & 7, lane = (t2 >> 3) & 63, nt = (t2 >> 9) & 7, kb = t2 >> 12;
      const int k = kb * 32 + (lane >> 4) * 8 + j;
      const int col = nt * 16 + (lane & 15);
      W2p[t2] = f2bfbits(W2[k * HID + col]);
    }
  }
}

__global__ __launch_bounds__(256, 5)
void edge_mlp(const float* __restrict__ z, const int* __restrict__ ei,
              const float* __restrict__ ea, const float* __restrict__ lre,
              const ushort* __restrict__ W1p, const float* __restrict__ b1,
              const ushort* __restrict__ W2p, const float* __restrict__ b2,
              const float* __restrict__ W3, const float* __restrict__ b3,
              float* __restrict__ out) {
  __shared__ ushort B0[ME * 128];  // 2 buffers * 16384B = 32768B -> 5 blocks/CU
  __shared__ ushort B1[ME * 128];

  const int tid = threadIdx.x;
  const int lane = tid & 63;
  const int w = tid >> 6;        // wave 0..3, owns output cols [32w, 32w+32)
  const int r15 = lane & 15;
  const int g = lane >> 4;
  const int half = lane >> 5;    // 0/1
  const int li = lane & 31;
  const int row0 = w * 16;       // edges this wave builds
  const int cw = w * 32;
  const int eb = blockIdx.x * ME;

  // ---- per-wave metadata: lanes 0..15 = src idx, 16..31 = dst idx,
  //      lanes 32..47 = dist(f32), 48..63 = lr_id(f32)
  int sd = 0;
  float auxv = 0.f;
  if (lane < 16)      sd = ei[eb + row0 + lane];
  else if (lane < 32) sd = ei[N_EDGES + eb + row0 + (lane - 16)];
  else if (lane < 48) auxv = ea[(eb + row0 + (lane - 32)) * 7 + 0];
  else                auxv = ea[(eb + row0 + (lane - 48)) * 7 + 2];

  // ---- P0: gather z rows (float4/lane, 2 edges per iter), convert to packed
  //      bf16 IMMEDIATELY (no f32 staging arrays -> no spills), zs->B0, zd->B1
  uint2 zs_pk[8], zd_pk[8];
#pragma unroll
  for (int t = 0; t < 8; ++t) {
    const int s = __shfl(sd, 2 * t + half);
    const float4 v = *(const float4*)(z + s * HID + 4 * li);
    zs_pk[t].x = cvtpk(v.x, v.y);
    zs_pk[t].y = cvtpk(v.z, v.w);
  }
#pragma unroll
  for (int t = 0; t < 8; ++t) {
    const int d = __shfl(sd, 16 + 2 * t + half);
    const float4 v = *(const float4*)(z + d * HID + 4 * li);
    zd_pk[t].x = cvtpk(v.x, v.y);
    zd_pk[t].y = cvtpk(v.z, v.w);
  }
#pragma unroll
  for (int t = 0; t < 8; ++t) {
    const int r = row0 + 2 * t + half;
    *(uint2*)&B0[sidx(r, 4 * li)] = zs_pk[t];
    *(uint2*)&B1[sidx(r, 4 * li)] = zd_pk[t];
  }
  __syncthreads();

  f32x4 acc[4][2];
#pragma unroll
  for (int mt = 0; mt < 4; ++mt) {
    acc[mt][0] = (f32x4){0.f, 0.f, 0.f, 0.f};
    acc[mt][1] = (f32x4){0.f, 0.f, 0.f, 0.f};
  }

#define MFMA_CHUNK(BUF, NKK, KB)                                                        \
  _Pragma("unroll")                                                                     \
  for (int kk = 0; kk < (NKK); ++kk) {                                                  \
    const int kbg = (KB) + kk;                                                          \
    short8 bfr0 = *(const short8*)(W1p + (((kbg * 8 + 2 * w) * 64) + lane) * 8);        \
    short8 bfr1 = *(const short8*)(W1p + (((kbg * 8 + 2 * w + 1) * 64) + lane) * 8);    \
    _Pragma("unroll")                                                                   \
    for (int mt = 0; mt < 4; ++mt) {                                                    \
      short8 af = *(const short8*)&BUF[sidx(mt * 16 + r15, kk * 32 + g * 8)];           \
      acc[mt][0] = __builtin_amdgcn_mfma_f32_16x16x32_bf16(af, bfr0, acc[mt][0], 0, 0, 0); \
      acc[mt][1] = __builtin_amdgcn_mfma_f32_16x16x32_bf16(af, bfr1, acc[mt][1], 0, 0, 0); \
    }                                                                                   \
  }

  // ---- P1: MFMA zs (kb 0..3)
  MFMA_CHUNK(B0, 4, 0)
  __syncthreads();

  // ---- P2: prod -> B0 (from regs); MFMA zd (kb 4..7)
#pragma unroll
  for (int t = 0; t < 8; ++t) {
    const int r = row0 + 2 * t + half;
    uint2 o;
    o.x = cvtpk(blo(zs_pk[t].x) * blo(zd_pk[t].x), bhi(zs_pk[t].x) * bhi(zd_pk[t].x));
    o.y = cvtpk(blo(zs_pk[t].y) * blo(zd_pk[t].y), bhi(zs_pk[t].y) * bhi(zd_pk[t].y));
    *(uint2*)&B0[sidx(r, 4 * li)] = o;
  }
  MFMA_CHUNK(B1, 4, 4)
  __syncthreads();

  // ---- P3: absdiff -> B1 (from regs); MFMA prod (kb 8..11)
#pragma unroll
  for (int t = 0; t < 8; ++t) {
    const int r = row0 + 2 * t + half;
    uint2 o;
    o.x = cvtpk(fabsf(blo(zs_pk[t].x) - blo(zd_pk[t].x)),
                fabsf(bhi(zs_pk[t].x) - bhi(zd_pk[t].x)));
    o.y = cvtpk(fabsf(blo(zs_pk[t].y) - blo(zd_pk[t].y)),
                fabsf(bhi(zs_pk[t].y) - bhi(zd_pk[t].y)));
    *(uint2*)&B1[sidx(r, 4 * li)] = o;
  }
  MFMA_CHUNK(B0, 4, 8)
  __syncthreads();

  // ---- P4: tail -> B0 (col0 = dist, cols 2..33 = lr_emb; rest = garbage * zero-weight);
  //      MFMA absdiff (kb 12..15)
  {
    const float dv = __shfl(auxv, 32 + r15);
    if (lane < 16) B0[sidx(row0 + lane, 0)] = f2bfbits(dv);
  }
#pragma unroll
  for (int t = 0; t < 4; ++t) {
    const int e = 4 * t + g;
    const int lrid = (int)__shfl(auxv, 48 + e);
    const float2 lv = *(const float2*)(lre + lrid * 32 + 2 * r15);
    *(uint*)&B0[sidx(row0 + e, 2 + 2 * r15)] = cvtpk(lv.x, lv.y);
  }
  MFMA_CHUNK(B1, 4, 12)
  __syncthreads();

  // ---- P5: MFMA tail (kb 16..17); h1 = relu(acc+b1) -> B1
  MFMA_CHUNK(B0, 2, 16)
  {
    const float b1v0 = b1[cw + r15];
    const float b1v1 = b1[cw + 16 + r15];
#pragma unroll
    for (int mt = 0; mt < 4; ++mt)
#pragma unroll
      for (int nt = 0; nt < 2; ++nt)
#pragma unroll
        for (int j = 0; j < 4; ++j) {
          const float h = acc[mt][nt][j] + (nt ? b1v1 : b1v0);
          B1[sidx(mt * 16 + g * 4 + j, cw + nt * 16 + r15)] = f2bfbits(fmaxf(h, 0.f));
        }
  }
  __syncthreads();

  // ---- P6: layer 2 (K=128) from B1; h2 -> B0
  f32x4 acc2[4][2];
#pragma unroll
  for (int mt = 0; mt < 4; ++mt) {
    acc2[mt][0] = (f32x4){0.f, 0.f, 0.f, 0.f};
    acc2[mt][1] = (f32x4){0.f, 0.f, 0.f, 0.f};
  }
#pragma unroll
  for (int kk = 0; kk < 4; ++kk) {
    short8 bfr0 = *(const short8*)(W2p + (((kk * 8 + 2 * w) * 64) + lane) * 8);
    short8 bfr1 = *(const short8*)(W2p + (((kk * 8 + 2 * w + 1) * 64) + lane) * 8);
#pragma unroll
    for (int mt = 0; mt < 4; ++mt) {
      short8 af = *(const short8*)&B1[sidx(mt * 16 + r15, kk * 32 + g * 8)];
      acc2[mt][0] = __builtin_amdgcn_mfma_f32_16x16x32_bf16(af, bfr0, acc2[mt][0], 0, 0, 0);
      acc2[mt][1] = __builtin_amdgcn_mfma_f32_16x16x32_bf16(af, bfr1, acc2[mt][1], 0, 0, 0);
    }
  }
  {
    const float b2v0 = b2[cw + r15];
    const float b2v1 = b2[cw + 16 + r15];
#pragma unroll
    for (int mt = 0; mt < 4; ++mt)
#pragma unroll
      for (int nt = 0; nt < 2; ++nt)
#pragma unroll
        for (int j = 0; j < 4; ++j) {
          const float h = acc2[mt][nt][j] + (nt ? b2v1 : b2v0);
          B0[sidx(mt * 16 + g * 4 + j, cw + nt * 16 + r15)] = f2bfbits(fmaxf(h, 0.f));
        }
  }
  __syncthreads();

  // ---- P7: layer 3: lane -> row w*16+r15, cols g*32..g*32+31, reduce over g
  {
    const int rr = w * 16 + r15;
    float sum = 0.f;
#pragma unroll
    for (int i = 0; i < 4; ++i) {
      const int c0 = g * 32 + i * 8;
      const uint4 hv = *(const uint4*)&B0[sidx(rr, c0)];
#pragma unroll
      for (int p = 0; p < 4; ++p) {
        const uint u = ((const uint*)&hv)[p];
        const float2 wv = *(const float2*)(W3 + c0 + 2 * p);
        sum += blo(u) * wv.x + bhi(u) * wv.y;
      }
    }
    sum += __shfl_xor(sum, 16);
    sum += __shfl_xor(sum, 32);
    if (lane < 16) out[eb + rr] = sum + b3[0];
  }
}

extern "C" void kernel_launch(void* const* d_in, const int* in_sizes, int n_in,
                              void* d_out, int out_size, void* d_ws, size_t ws_size,
                              hipStream_t stream) {
  const float* z   = (const float*)d_in[0];
  const int*   ei  = (const int*)d_in[1];
  const float* ea  = (const float*)d_in[2];
  const float* lre = (const float*)d_in[3];
  const float* W1  = (const float*)d_in[4];
  const float* b1  = (const float*)d_in[5];
  const float* W2  = (const float*)d_in[6];
  const float* b2  = (const float*)d_in[7];
  const float* W3  = (const float*)d_in[8];
  const float* b3  = (const float*)d_in[9];
  float* out = (float*)d_out;

  ushort* W1p = (ushort*)d_ws;              // 18*8*64*8 = 73728 bf16
  ushort* W2p = W1p + 18 * 8 * 64 * 8;      // 4*8*64*8  = 16384 bf16

  prep_kernel<<<352, 256, 0, stream>>>(W1, W2, W1p, W2p);
  edge_mlp<<<N_EDGES / ME, 256, 0, stream>>>(z, ei, ea, lre, W1p, b1, W2p, b2, W3, b3, out);
}

// Round 4
// 290.337 us; speedup vs baseline: 1.8090x; 1.8090x over previous
//
#include <hip/hip_runtime.h>

#define N_EDGES 1000000
#define HID 128
#define ME 64          // edges per block

typedef unsigned short ushort;
typedef unsigned int uint;
typedef __attribute__((ext_vector_type(8))) short short8;
typedef __attribute__((ext_vector_type(4))) float f32x4;

__device__ __forceinline__ float blo(uint u) { return __builtin_bit_cast(float, u << 16); }
__device__ __forceinline__ float bhi(uint u) { return __builtin_bit_cast(float, u & 0xffff0000u); }
__device__ __forceinline__ ushort f2bfbits(float f) {
  uint u = __builtin_bit_cast(uint, f);
  return (ushort)((u + 0x7fffu + ((u >> 16) & 1u)) >> 16);  // RNE
}
__device__ __forceinline__ uint cvtpk(float a, float b) {
  uint r;
  asm("v_cvt_pk_bf16_f32 %0, %1, %2" : "=v"(r) : "v"(a), "v"(b));
  return r;  // lo = bf16(a), hi = bf16(b)
}
// XOR-swizzled element index into a [64][128] ushort LDS tile.
__device__ __forceinline__ int sidx(int r, int c) {
  return r * 128 + (c ^ ((r & 7) << 3));
}

// Pack W (row-major [K][128] f32) into B-fragment order for mfma_f32_16x16x32_bf16.
// W1p kb 0..15: k = kb*32 + (lane>>4)*8 + j (zs,zd,prod,absdiff).
// W1p kb 16..17 (tail chunk, 64 cols): c = (kb-16)*32+(lane>>4)*8+j;
//   c==0 -> k512 (dist); c in [2,34) -> k 511+c (lr_emb); else zero row.
__global__ void prep_kernel(const float* __restrict__ W1, const float* __restrict__ W2,
                            ushort* __restrict__ W1p, ushort* __restrict__ W2p) {
  const int t = blockIdx.x * blockDim.x + threadIdx.x;
  const int n1 = 18 * 8 * 64 * 8;
  if (t < n1) {
    const int j = t & 7, lane = (t >> 3) & 63, nt = (t >> 9) & 7, kb = t >> 12;
    const int col = nt * 16 + (lane & 15);
    float val = 0.f;
    if (kb < 16) {
      const int k = kb * 32 + (lane >> 4) * 8 + j;
      val = W1[k * HID + col];
    } else {
      const int c = (kb - 16) * 32 + (lane >> 4) * 8 + j;
      const int k = (c == 0) ? 512 : ((c >= 2 && c < 34) ? (511 + c) : -1);
      if (k >= 0) val = W1[k * HID + col];
    }
    W1p[t] = f2bfbits(val);
  } else {
    const int t2 = t - n1;
    if (t2 < 4 * 8 * 64 * 8) {
      const int j = t2 & 7, lane = (t2 >> 3) & 63, nt = (t2 >> 9) & 7, kb = t2 >> 12;
      const int k = kb * 32 + (lane >> 4) * 8 + j;
      const int col = nt * 16 + (lane & 15);
      W2p[t2] = f2bfbits(W2[k * HID + col]);
    }
  }
}

// 3 waves/EU -> reg cap ~170 incl. AGPRs: fits acc(32 AGPR)+acc2(32 AGPR)
// +zs/zd packed(32)+transients with NO scratch spill (R2/R3 lesson: caps 128/102 spilled).
__global__ __launch_bounds__(256, 3)
void edge_mlp(const float* __restrict__ z, const int* __restrict__ ei,
              const float* __restrict__ ea, const float* __restrict__ lre,
              const ushort* __restrict__ W1p, const float* __restrict__ b1,
              const ushort* __restrict__ W2p, const float* __restrict__ b2,
              const float* __restrict__ W3, const float* __restrict__ b3,
              float* __restrict__ out) {
  __shared__ ushort B0[ME * 128];  // 2 buffers * 16384B = 32768B
  __shared__ ushort B1[ME * 128];

  const int tid = threadIdx.x;
  const int lane = tid & 63;
  const int w = tid >> 6;        // wave 0..3, owns output cols [32w, 32w+32)
  const int r15 = lane & 15;
  const int g = lane >> 4;
  const int half = lane >> 5;    // 0/1
  const int li = lane & 31;
  const int row0 = w * 16;       // edges this wave builds
  const int cw = w * 32;
  const int eb = blockIdx.x * ME;

  // ---- per-wave metadata: lanes 0..15 = src idx, 16..31 = dst idx,
  //      lanes 32..47 = dist(f32), 48..63 = lr_id(f32)
  int sd = 0;
  float auxv = 0.f;
  if (lane < 16)      sd = ei[eb + row0 + lane];
  else if (lane < 32) sd = ei[N_EDGES + eb + row0 + (lane - 16)];
  else if (lane < 48) auxv = ea[(eb + row0 + (lane - 32)) * 7 + 0];
  else                auxv = ea[(eb + row0 + (lane - 48)) * 7 + 2];

  // ---- P0: gather z rows (float4/lane, 2 edges per iter), convert to packed
  //      bf16 immediately, zs->B0, zd->B1
  uint2 zs_pk[8], zd_pk[8];
#pragma unroll
  for (int t = 0; t < 8; ++t) {
    const int s = __shfl(sd, 2 * t + half);
    const float4 v = *(const float4*)(z + s * HID + 4 * li);
    zs_pk[t].x = cvtpk(v.x, v.y);
    zs_pk[t].y = cvtpk(v.z, v.w);
  }
#pragma unroll
  for (int t = 0; t < 8; ++t) {
    const int d = __shfl(sd, 16 + 2 * t + half);
    const float4 v = *(const float4*)(z + d * HID + 4 * li);
    zd_pk[t].x = cvtpk(v.x, v.y);
    zd_pk[t].y = cvtpk(v.z, v.w);
  }
#pragma unroll
  for (int t = 0; t < 8; ++t) {
    const int r = row0 + 2 * t + half;
    *(uint2*)&B0[sidx(r, 4 * li)] = zs_pk[t];
    *(uint2*)&B1[sidx(r, 4 * li)] = zd_pk[t];
  }
  __syncthreads();

  f32x4 acc[4][2];
#pragma unroll
  for (int mt = 0; mt < 4; ++mt) {
    acc[mt][0] = (f32x4){0.f, 0.f, 0.f, 0.f};
    acc[mt][1] = (f32x4){0.f, 0.f, 0.f, 0.f};
  }

#define MFMA_CHUNK(BUF, NKK, KB)                                                        \
  __builtin_amdgcn_s_setprio(1);                                                        \
  _Pragma("unroll")                                                                     \
  for (int kk = 0; kk < (NKK); ++kk) {                                                  \
    const int kbg = (KB) + kk;                                                          \
    short8 bfr0 = *(const short8*)(W1p + (((kbg * 8 + 2 * w) * 64) + lane) * 8);        \
    short8 bfr1 = *(const short8*)(W1p + (((kbg * 8 + 2 * w + 1) * 64) + lane) * 8);    \
    _Pragma("unroll")                                                                   \
    for (int mt = 0; mt < 4; ++mt) {                                                    \
      short8 af = *(const short8*)&BUF[sidx(mt * 16 + r15, kk * 32 + g * 8)];           \
      acc[mt][0] = __builtin_amdgcn_mfma_f32_16x16x32_bf16(af, bfr0, acc[mt][0], 0, 0, 0); \
      acc[mt][1] = __builtin_amdgcn_mfma_f32_16x16x32_bf16(af, bfr1, acc[mt][1], 0, 0, 0); \
    }                                                                                   \
  }                                                                                     \
  __builtin_amdgcn_s_setprio(0);

  // ---- P1: MFMA zs (kb 0..3)
  MFMA_CHUNK(B0, 4, 0)
  __syncthreads();

  // ---- P2: prod -> B0 (from regs); MFMA zd (kb 4..7)
#pragma unroll
  for (int t = 0; t < 8; ++t) {
    const int r = row0 + 2 * t + half;
    uint2 o;
    o.x = cvtpk(blo(zs_pk[t].x) * blo(zd_pk[t].x), bhi(zs_pk[t].x) * bhi(zd_pk[t].x));
    o.y = cvtpk(blo(zs_pk[t].y) * blo(zd_pk[t].y), bhi(zs_pk[t].y) * bhi(zd_pk[t].y));
    *(uint2*)&B0[sidx(r, 4 * li)] = o;
  }
  MFMA_CHUNK(B1, 4, 4)
  __syncthreads();

  // ---- P3: absdiff -> B1 (from regs); MFMA prod (kb 8..11)
#pragma unroll
  for (int t = 0; t < 8; ++t) {
    const int r = row0 + 2 * t + half;
    uint2 o;
    o.x = cvtpk(fabsf(blo(zs_pk[t].x) - blo(zd_pk[t].x)),
                fabsf(bhi(zs_pk[t].x) - bhi(zd_pk[t].x)));
    o.y = cvtpk(fabsf(blo(zs_pk[t].y) - blo(zd_pk[t].y)),
                fabsf(bhi(zs_pk[t].y) - bhi(zd_pk[t].y)));
    *(uint2*)&B1[sidx(r, 4 * li)] = o;
  }
  MFMA_CHUNK(B0, 4, 8)
  __syncthreads();

  // ---- P4: tail -> B0 (col0 = dist, cols 2..33 = lr_emb; rest = garbage * zero-weight);
  //      MFMA absdiff (kb 12..15)
  {
    const float dv = __shfl(auxv, 32 + r15);
    if (lane < 16) B0[sidx(row0 + lane, 0)] = f2bfbits(dv);
  }
#pragma unroll
  for (int t = 0; t < 4; ++t) {
    const int e = 4 * t + g;
    const int lrid = (int)__shfl(auxv, 48 + e);
    const float2 lv = *(const float2*)(lre + lrid * 32 + 2 * r15);
    *(uint*)&B0[sidx(row0 + e, 2 + 2 * r15)] = cvtpk(lv.x, lv.y);
  }
  MFMA_CHUNK(B1, 4, 12)
  __syncthreads();

  // ---- P5: MFMA tail (kb 16..17); h1 = relu(acc+b1) -> B1
  MFMA_CHUNK(B0, 2, 16)
  {
    const float b1v0 = b1[cw + r15];
    const float b1v1 = b1[cw + 16 + r15];
#pragma unroll
    for (int mt = 0; mt < 4; ++mt)
#pragma unroll
      for (int nt = 0; nt < 2; ++nt)
#pragma unroll
        for (int j = 0; j < 4; ++j) {
          const float h = acc[mt][nt][j] + (nt ? b1v1 : b1v0);
          B1[sidx(mt * 16 + g * 4 + j, cw + nt * 16 + r15)] = f2bfbits(fmaxf(h, 0.f));
        }
  }
  __syncthreads();

  // ---- P6: layer 2 (K=128) from B1; h2 -> B0
  f32x4 acc2[4][2];
#pragma unroll
  for (int mt = 0; mt < 4; ++mt) {
    acc2[mt][0] = (f32x4){0.f, 0.f, 0.f, 0.f};
    acc2[mt][1] = (f32x4){0.f, 0.f, 0.f, 0.f};
  }
  __builtin_amdgcn_s_setprio(1);
#pragma unroll
  for (int kk = 0; kk < 4; ++kk) {
    short8 bfr0 = *(const short8*)(W2p + (((kk * 8 + 2 * w) * 64) + lane) * 8);
    short8 bfr1 = *(const short8*)(W2p + (((kk * 8 + 2 * w + 1) * 64) + lane) * 8);
#pragma unroll
    for (int mt = 0; mt < 4; ++mt) {
      short8 af = *(const short8*)&B1[sidx(mt * 16 + r15, kk * 32 + g * 8)];
      acc2[mt][0] = __builtin_amdgcn_mfma_f32_16x16x32_bf16(af, bfr0, acc2[mt][0], 0, 0, 0);
      acc2[mt][1] = __builtin_amdgcn_mfma_f32_16x16x32_bf16(af, bfr1, acc2[mt][1], 0, 0, 0);
    }
  }
  __builtin_amdgcn_s_setprio(0);
  {
    const float b2v0 = b2[cw + r15];
    const float b2v1 = b2[cw + 16 + r15];
#pragma unroll
    for (int mt = 0; mt < 4; ++mt)
#pragma unroll
      for (int nt = 0; nt < 2; ++nt)
#pragma unroll
        for (int j = 0; j < 4; ++j) {
          const float h = acc2[mt][nt][j] + (nt ? b2v1 : b2v0);
          B0[sidx(mt * 16 + g * 4 + j, cw + nt * 16 + r15)] = f2bfbits(fmaxf(h, 0.f));
        }
  }
  __syncthreads();

  // ---- P7: layer 3: lane -> row w*16+r15, cols g*32..g*32+31, reduce over g
  {
    const int rr = w * 16 + r15;
    float sum = 0.f;
#pragma unroll
    for (int i = 0; i < 4; ++i) {
      const int c0 = g * 32 + i * 8;
      const uint4 hv = *(const uint4*)&B0[sidx(rr, c0)];
#pragma unroll
      for (int p = 0; p < 4; ++p) {
        const uint u = ((const uint*)&hv)[p];
        const float2 wv = *(const float2*)(W3 + c0 + 2 * p);
        sum += blo(u) * wv.x + bhi(u) * wv.y;
      }
    }
    sum += __shfl_xor(sum, 16);
    sum += __shfl_xor(sum, 32);
    if (lane < 16) out[eb + rr] = sum + b3[0];
  }
}

extern "C" void kernel_launch(void* const* d_in, const int* in_sizes, int n_in,
                              void* d_out, int out_size, void* d_ws, size_t ws_size,
                              hipStream_t stream) {
  const float* z   = (const float*)d_in[0];
  const int*   ei  = (const int*)d_in[1];
  const float* ea  = (const float*)d_in[2];
  const float* lre = (const float*)d_in[3];
  const float* W1  = (const float*)d_in[4];
  const float* b1  = (const float*)d_in[5];
  const float* W2  = (const float*)d_in[6];
  const float* b2  = (const float*)d_in[7];
  const float* W3  = (const float*)d_in[8];
  const float* b3  = (const float*)d_in[9];
  float* out = (float*)d_out;

  ushort* W1p = (ushort*)d_ws;              // 18*8*64*8 = 73728 bf16
  ushort* W2p = W1p + 18 * 8 * 64 * 8;      // 4*8*64*8  = 16384 bf16

  prep_kernel<<<352, 256, 0, stream>>>(W1, W2, W1p, W2p);
  edge_mlp<<<N_EDGES / ME, 256, 0, stream>>>(z, ei, ea, lre, W1p, b1, W2p, b2, W3, b3, out);
}